// Round 1
// baseline (312.773 us; speedup 1.0000x reference)
//
#include <hip/hip_runtime.h>
#include <hip/hip_bf16.h>
#include <stdint.h>

// TinyMod fused: x[8192,4096] -> (fcin 32x32) -> 32x blockwise Linear(128->128) -> (fcout 32x32)
// Fully fused in one kernel, bf16 MFMA (16x16x32), fp32 accumulate, fp32 out.
// WG = 16 batch rows x 512 threads (8 waves). Grid = 512.

#define BT    16
#define NTHR  512
#define GRID  512      // 8192 / BT
#define IDIM  4096
#define ODIM  4096

typedef __attribute__((ext_vector_type(8))) __bf16 bf16x8;
typedef __attribute__((ext_vector_type(4))) float  floatx4;

union BF8 { uint32_t w[4]; unsigned short h[8]; bf16x8 v; };

__device__ __forceinline__ unsigned short f2bf(float f) {
    uint32_t u = __builtin_bit_cast(uint32_t, f);
    u += 0x7fffu + ((u >> 16) & 1u);   // RNE
    return (unsigned short)(u >> 16);
}

// ylds: y[c][bt][m], bf16. bt-pitch 132, c-pitch 2116 (dword-bank stride 2 -> <=4-way aliasing)
#define YP_BT 132
#define YP_C  2116
// scratch union:
//   xchunk: [m':16][bt:16][i:32] -> (m'*16+bt)*32 + i   (64B contiguous per (m',bt) row)
//   wchunk: [n':16][bt:16][c:32] -> n'*584 + bt*36 + c  (c-contiguous for stage-3 K-frags)
#define WP_BT 36
#define WP_N  584
#define SCR_ELEMS (16 * WP_N)   // 9344 elems >= 8192 needed by xchunk

template<bool WBF16>
__global__ __launch_bounds__(NTHR, 1)
void tinymod_fused(const float* __restrict__ x,
                   const float* __restrict__ W_in,
                   const float* __restrict__ b_in,
                   const void*  __restrict__ wmods,
                   const float* __restrict__ b_mods,
                   const float* __restrict__ W_out,
                   const float* __restrict__ b_out,
                   float* __restrict__ out)
{
    __shared__ unsigned short ylds[32 * YP_C] __attribute__((aligned(16)));
    __shared__ unsigned short scr[SCR_ELEMS]  __attribute__((aligned(16)));

    const int tid  = threadIdx.x;
    const int lane = tid & 63;
    const int wave = tid >> 6;          // 0..7
    const int l15  = lane & 15;
    const int grp  = lane >> 4;         // 0..3
    const int row0 = blockIdx.x * BT;

    // ---- tiny operand preloads (held in VGPRs whole kernel) ----
    const float bin0 = b_in[l15],  bin1 = b_in[16 + l15];
    const float bo0  = b_out[l15], bo1  = b_out[16 + l15];
    BF8 winf[2], woutf[2];
    #pragma unroll
    for (int cc = 0; cc < 2; cc++) {
        const float* p = W_in  + (l15 + 16*cc) * 32 + grp * 8;  // B[k=i][col=c]
        const float* q = W_out + (l15 + 16*cc) * 32 + grp * 8;  // B[k=c][col=o]
        #pragma unroll
        for (int j = 0; j < 8; j++) { winf[cc].h[j] = f2bf(p[j]); woutf[cc].h[j] = f2bf(q[j]); }
    }

    // ---------------- Stage 1: x -> y (fcin), 8 m-blocks of 16 ----------------
    // staging assignment: thread t loads x[row0+sbt][i*128 + m0+smp] for 16 i's
    const int smp = tid & 15;
    const int sbt = (tid >> 4) & 15;
    const int sih = tid >> 8;           // 0/1
    const float* xb = x + (row0 + sbt) * IDIM + smp;

    float xr[16];
    #pragma unroll
    for (int p = 0; p < 2; p++) {
        const int i0 = (sih + 2*p) * 8;
        #pragma unroll
        for (int j = 0; j < 8; j++) xr[p*8 + j] = xb[(i0 + j) * 128];
    }

    for (int mb = 0; mb < 8; mb++) {
        // write staged regs -> xchunk (bf16, ds_write_b128)
        #pragma unroll
        for (int p = 0; p < 2; p++) {
            const int i0 = (sih + 2*p) * 8;
            BF8 t;
            #pragma unroll
            for (int j = 0; j < 8; j++) t.h[j] = f2bf(xr[p*8 + j]);
            uint4 val; val.x = t.w[0]; val.y = t.w[1]; val.z = t.w[2]; val.w = t.w[3];
            *(uint4*)&scr[(smp*16 + sbt)*32 + i0] = val;
        }
        __syncthreads();

        // prefetch next m-block (latency overlapped with MFMA below)
        float xr2[16];
        if (mb < 7) {
            #pragma unroll
            for (int p = 0; p < 2; p++) {
                const int i0 = (sih + 2*p) * 8;
                #pragma unroll
                for (int j = 0; j < 8; j++) xr2[p*8 + j] = xb[(i0 + j) * 128 + (mb + 1) * 16];
            }
        }

        // compute: wave handles m' = 2*wave + {0,1}
        unsigned short yh[2][2][4];
        #pragma unroll
        for (int mm = 0; mm < 2; mm++) {
            const int mp = 2*wave + mm;
            BF8 a;
            const uint4 av = *(const uint4*)&scr[(mp*16 + l15)*32 + grp*8]; // A[bt=l15][k=i]
            a.w[0] = av.x; a.w[1] = av.y; a.w[2] = av.z; a.w[3] = av.w;
            #pragma unroll
            for (int cc = 0; cc < 2; cc++) {
                floatx4 acc = {0.f, 0.f, 0.f, 0.f};
                acc = __builtin_amdgcn_mfma_f32_16x16x32_bf16(a.v, winf[cc].v, acc, 0, 0, 0);
                const float bi = cc ? bin1 : bin0;
                #pragma unroll
                for (int r = 0; r < 4; r++) yh[mm][cc][r] = f2bf(acc[r] + bi);
            }
        }
        // y -> ylds: pack the m' pair into one b32 write
        #pragma unroll
        for (int cc = 0; cc < 2; cc++)
            #pragma unroll
            for (int r = 0; r < 4; r++) {
                const int c  = l15 + 16*cc;
                const int bt = grp*4 + r;
                const uint32_t pk = (uint32_t)yh[0][cc][r] | ((uint32_t)yh[1][cc][r] << 16);
                *(uint32_t*)&ylds[c*YP_C + bt*YP_BT + mb*16 + 2*wave] = pk;
            }
        __syncthreads();
        if (mb < 7) {
            #pragma unroll
            for (int q = 0; q < 16; q++) xr[q] = xr2[q];
        }
    }

    // ---------------- Stage 2+3: y -> w -> out, 8 n-blocks of 16 ----------------
    const unsigned short* __restrict__ wm16 = (const unsigned short*)wmods;
    const float*          __restrict__ wm32 = (const float*)wmods;

    for (int nb = 0; nb < 8; nb++) {
        // stage 2: wave owns c = 4*wave + ci
        floatx4 acc[4];
        float   bm[4];
        #pragma unroll
        for (int ci = 0; ci < 4; ci++) {
            const int c = 4*wave + ci;
            bm[ci] = b_mods[c*128 + nb*16 + l15];
            const int ybase = c*YP_C + l15*YP_BT + grp*8;              // A[bt=l15][k=m]
            const int wbase = (c*128 + nb*16 + l15)*128 + grp*8;       // B[k=m][col=n=l15]
            floatx4 s = {0.f, 0.f, 0.f, 0.f};
            #pragma unroll
            for (int kc = 0; kc < 4; kc++) {
                BF8 a;
                const uint2 u0 = *(const uint2*)&ylds[ybase + kc*32];
                const uint2 u1 = *(const uint2*)&ylds[ybase + kc*32 + 4];
                a.w[0] = u0.x; a.w[1] = u0.y; a.w[2] = u1.x; a.w[3] = u1.y;
                BF8 b;
                if (WBF16) {
                    const uint4 bv = *(const uint4*)&wm16[wbase + kc*32];
                    b.w[0] = bv.x; b.w[1] = bv.y; b.w[2] = bv.z; b.w[3] = bv.w;
                } else {
                    const float* wp = wm32 + wbase + kc*32;
                    #pragma unroll
                    for (int j = 0; j < 8; j++) b.h[j] = f2bf(wp[j]);
                }
                s = __builtin_amdgcn_mfma_f32_16x16x32_bf16(a.v, b.v, s, 0, 0, 0);
            }
            acc[ci] = s;
        }
        // w -> wchunk: batch the wave's 4 contiguous c into one b64 write
        #pragma unroll
        for (int r = 0; r < 4; r++) {
            unsigned short h[4];
            #pragma unroll
            for (int ci = 0; ci < 4; ci++) h[ci] = f2bf(acc[ci][r] + bm[ci]);
            uint2 pk;
            pk.x = (uint32_t)h[0] | ((uint32_t)h[1] << 16);
            pk.y = (uint32_t)h[2] | ((uint32_t)h[3] << 16);
            *(uint2*)&scr[l15*WP_N + (grp*4 + r)*WP_BT + 4*wave] = pk;
        }
        __syncthreads();

        // stage 3: wave handles m' = 2*wave + {0,1}; K = c = 32 in one MFMA
        #pragma unroll
        for (int mm = 0; mm < 2; mm++) {
            const int mp = 2*wave + mm;
            BF8 a;
            const int off = mp*WP_N + l15*WP_BT + grp*8;               // A[bt=l15][k=c]
            const uint2 u0 = *(const uint2*)&scr[off];
            const uint2 u1 = *(const uint2*)&scr[off + 4];
            a.w[0] = u0.x; a.w[1] = u0.y; a.w[2] = u1.x; a.w[3] = u1.y;
            #pragma unroll
            for (int oc = 0; oc < 2; oc++) {
                floatx4 v = {0.f, 0.f, 0.f, 0.f};
                v = __builtin_amdgcn_mfma_f32_16x16x32_bf16(a.v, woutf[oc].v, v, 0, 0, 0);
                const float bo = oc ? bo1 : bo0;
                float* po = out + row0*ODIM + (nb*16 + mp)*32 + l15 + 16*oc;
                #pragma unroll
                for (int r = 0; r < 4; r++) {
                    const int bt = grp*4 + r;
                    po[bt*ODIM] = v[r] + bo;   // 16 lanes x 4B = 64B segments
                }
            }
        }
        __syncthreads();   // wchunk reused next nb
    }
}

// prologue: W_mods fp32 -> bf16 into workspace (2 MiB -> 1 MiB, L2/L3 resident)
__global__ void wmods_to_bf16(const float* __restrict__ w, unsigned short* __restrict__ o) {
    const int i = (blockIdx.x * 256 + threadIdx.x) * 4;
    const float4 f = *(const float4*)(w + i);
    uint2 pk;
    pk.x = (uint32_t)f2bf(f.x) | ((uint32_t)f2bf(f.y) << 16);
    pk.y = (uint32_t)f2bf(f.z) | ((uint32_t)f2bf(f.w) << 16);
    *(uint2*)(o + i) = pk;
}

extern "C" void kernel_launch(void* const* d_in, const int* in_sizes, int n_in,
                              void* d_out, int out_size, void* d_ws, size_t ws_size,
                              hipStream_t stream)
{
    const float* x     = (const float*)d_in[0];
    const float* W_in  = (const float*)d_in[1];
    const float* b_in  = (const float*)d_in[2];
    const float* Wm    = (const float*)d_in[3];
    const float* b_m   = (const float*)d_in[4];
    const float* W_out = (const float*)d_in[5];
    const float* b_out = (const float*)d_in[6];
    float* out = (float*)d_out;

    const size_t wm_elems = 32u * 128u * 128u;   // 524288
    if (ws_size >= wm_elems * sizeof(unsigned short)) {
        unsigned short* wbf = (unsigned short*)d_ws;
        wmods_to_bf16<<<(int)(wm_elems / (256 * 4)), 256, 0, stream>>>(Wm, wbf);
        tinymod_fused<true><<<GRID, NTHR, 0, stream>>>(x, W_in, b_in, (const void*)wbf,
                                                       b_m, W_out, b_out, out);
    } else {
        tinymod_fused<false><<<GRID, NTHR, 0, stream>>>(x, W_in, b_in, (const void*)Wm,
                                                        b_m, W_out, b_out, out);
    }
}